// Round 1
// 640.475 us; speedup vs baseline: 1.1295x; 1.1295x over previous
//
#include <hip/hip_runtime.h>
#include <hip/hip_bf16.h>
#include <cstdint>
#include <cstddef>

// ---------------------------------------------------------------------------
// MoL model fused kernel set for MI355X (gfx950)
//
// out = x @ W^T + b + sum_{e,r} softmax_e(q_e.k_e/sqrt(DK)) * (x.A[e,r]) * Bm[e,:,r]
//
//   A_ext[m, 0:4096]   = bf16(x)          (lda = 4224)
//   A_ext[m, 4096+j]   = g[m,j] = w_e * h[e,r] * SCALING   (j = e*16+r)
//   W_ext[n, 0:4096]   = bf16(W)          (ldb = 4224)
//   W_ext[n, 4096+j]   = bf16(Bm[e,n,r])
//   out = A_ext @ W_ext^T + b   -- single K=4224 GEMM (LoRA fused into K-tail)
//   P   = x_bf16 @ [Wq;Wk;A]^T  -- K=4096, N=640 GEMM feeding routing kernel
//
// This round: main GEMM ported to the 256x256 8-phase template
// (T1 XCD swizzle + T2 LDS swizzle + T3/T4 counted vmcnt + T5 setprio).
// ---------------------------------------------------------------------------

#define T_TOK   8192
#define DIN     4096
#define DOUT    4096
#define KEXT    4224          // 4096 + 128
#define NQKA    640           // 256 q + 256 k + 128 h
#define SCALING 1.0f

typedef __attribute__((ext_vector_type(8))) short bf16x8;
typedef __attribute__((ext_vector_type(4))) float f32x4;

__device__ __forceinline__ unsigned short f2bf(float f) {
    __hip_bfloat16 h = __float2bfloat16(f);
    return *reinterpret_cast<unsigned short*>(&h);
}

__device__ __forceinline__ void load_lds16(const void* g, void* l) {
    __builtin_amdgcn_global_load_lds((__attribute__((address_space(1))) void*)g,
                                     (__attribute__((address_space(3))) void*)l,
                                     16, 0, 0);
}

// ---- prep: x fp32 -> bf16 into A_ext rows (stride KEXT) ----
__global__ __launch_bounds__(256) void conv_x(const float4* __restrict__ x,
                                              unsigned short* __restrict__ Aext) {
    int t = blockIdx.x * 256 + threadIdx.x;      // T_TOK*1024 threads
    int row = t >> 10, c4 = t & 1023;
    float4 v = x[(size_t)row * 1024 + c4];
    ushort4 o;
    o.x = f2bf(v.x); o.y = f2bf(v.y); o.z = f2bf(v.z); o.w = f2bf(v.w);
    *(ushort4*)&Aext[(size_t)row * KEXT + c4 * 4] = o;
}

// ---- prep: W fp32 -> bf16 into W_ext rows (stride KEXT) ----
__global__ __launch_bounds__(256) void conv_w(const float4* __restrict__ W,
                                              unsigned short* __restrict__ Wext) {
    int t = blockIdx.x * 256 + threadIdx.x;      // DOUT*1024 threads
    int row = t >> 10, c4 = t & 1023;
    float4 v = W[(size_t)row * 1024 + c4];
    ushort4 o;
    o.x = f2bf(v.x); o.y = f2bf(v.y); o.z = f2bf(v.z); o.w = f2bf(v.w);
    *(ushort4*)&Wext[(size_t)row * KEXT + c4 * 4] = o;
}

// ---- prep: Bm[e,o,r]*SCALING -> W_ext[o, 4096 + e*16 + r] ----
__global__ __launch_bounds__(256) void fill_bm(const float* __restrict__ Bm,
                                               unsigned short* __restrict__ Wext) {
    int t = blockIdx.x * 256 + threadIdx.x;      // DOUT*128 threads
    int o = t >> 7, j = t & 127;
    int e = j >> 4, r = j & 15;
    float v = Bm[(size_t)e * (DOUT * 16) + (size_t)o * 16 + r] * SCALING;
    Wext[(size_t)o * KEXT + DIN + j] = f2bf(v);
}

// ---- prep: [Wq; Wk; A] fp32 -> bf16, packed rows stride 4096 ----
__global__ __launch_bounds__(256) void conv_wqka(const float4* __restrict__ Wq,
                                                 const float4* __restrict__ Wk,
                                                 const float4* __restrict__ Alora,
                                                 unsigned short* __restrict__ Wqka) {
    int t = blockIdx.x * 256 + threadIdx.x;      // NQKA*1024 threads
    int row = t >> 10, c4 = t & 1023;
    float4 v;
    if (row < 256)       v = Wq[(size_t)row * 1024 + c4];
    else if (row < 512)  v = Wk[(size_t)(row - 256) * 1024 + c4];
    else                 v = Alora[(size_t)(row - 512) * 1024 + c4];
    ushort4 o;
    o.x = f2bf(v.x); o.y = f2bf(v.y); o.z = f2bf(v.z); o.w = f2bf(v.w);
    *(ushort4*)&Wqka[(size_t)row * 4096 + c4 * 4] = o;
}

// ---- routing: P[token, 640] -> g[token, 128] bf16 appended to A_ext ----
__global__ __launch_bounds__(64) void routing(const float* __restrict__ P,
                                              unsigned short* __restrict__ Aext) {
    int token = blockIdx.x;
    const float* p = P + (size_t)token * NQKA;
    int l = threadIdx.x;
    int e = l >> 3, s = l & 7;
    float pp = 0.f;
#pragma unroll
    for (int j = 0; j < 4; j++) {
        int d = e * 32 + s * 4 + j;
        pp += p[d] * p[256 + d];
    }
    pp += __shfl_xor(pp, 4);
    pp += __shfl_xor(pp, 2);
    pp += __shfl_xor(pp, 1);
    float score = pp * 0.17677669529663687f;   // 1/sqrt(32)
    float mx = score;
    mx = fmaxf(mx, __shfl_xor(mx, 8));
    mx = fmaxf(mx, __shfl_xor(mx, 16));
    mx = fmaxf(mx, __shfl_xor(mx, 32));
    float ex = expf(score - mx);
    float sm = ex;
    sm += __shfl_xor(sm, 8);
    sm += __shfl_xor(sm, 16);
    sm += __shfl_xor(sm, 32);
    float w = ex / sm;
    __shared__ float sw[8];
    if (s == 0) sw[e] = w;
    __syncthreads();
    unsigned short* g = Aext + (size_t)token * KEXT + DIN;
#pragma unroll
    for (int i = 0; i < 2; i++) {
        int j = l + i * 64;
        float val = sw[j >> 4] * p[512 + j] * SCALING;
        g[j] = f2bf(val);
    }
}

// ---- small GEMM (P path): C[M,N] = A[M,K] @ B[N,K]^T, m97 128x128 recipe ----
__global__ __launch_bounds__(256, 2)
void gemm_bt(const unsigned short* __restrict__ A,
             const unsigned short* __restrict__ B,
             float* __restrict__ C,
             const float* __restrict__ bias,
             int lda, int ldb, int N, int K) {
    __shared__ unsigned short ldsA[128 * 32];
    __shared__ unsigned short ldsB[128 * 32];
    const int t = threadIdx.x;
    const int m0 = blockIdx.y * 128;
    const int n0 = blockIdx.x * 128;
    const int wave = t >> 6, lane = t & 63;
    const int wm = (wave >> 1) * 64, wn = (wave & 1) * 64;
    const int fr = lane & 15, quad = lane >> 4;

    f32x4 acc[4][4];
#pragma unroll
    for (int i = 0; i < 4; i++)
#pragma unroll
        for (int j = 0; j < 4; j++) acc[i][j] = (f32x4){0.f, 0.f, 0.f, 0.f};

    const unsigned short* aptr = A + (size_t)(m0 + (t >> 2)) * lda + (t & 3) * 8;
    const unsigned short* bptr = B + (size_t)(n0 + (t >> 2)) * ldb + (t & 3) * 8;
    char* ldsAb = (char*)ldsA + t * 16;
    char* ldsBb = (char*)ldsB + t * 16;

    for (int k0 = 0; k0 < K; k0 += 32) {
        load_lds16(aptr, ldsAb);
        load_lds16(aptr + 64 * (size_t)lda, ldsAb + 4096);
        load_lds16(bptr, ldsBb);
        load_lds16(bptr + 64 * (size_t)ldb, ldsBb + 4096);
        aptr += 32; bptr += 32;
        __syncthreads();

        bf16x8 af[4], bfr[4];
#pragma unroll
        for (int i = 0; i < 4; i++)
            af[i] = *(const bf16x8*)(ldsA + (wm + i * 16 + fr) * 32 + quad * 8);
#pragma unroll
        for (int j = 0; j < 4; j++)
            bfr[j] = *(const bf16x8*)(ldsB + (wn + j * 16 + fr) * 32 + quad * 8);
#pragma unroll
        for (int i = 0; i < 4; i++)
#pragma unroll
            for (int j = 0; j < 4; j++)
                acc[i][j] = __builtin_amdgcn_mfma_f32_16x16x32_bf16(af[i], bfr[j], acc[i][j], 0, 0, 0);
        __syncthreads();
    }

#pragma unroll
    for (int j = 0; j < 4; j++) {
        int col = n0 + wn + j * 16 + fr;
        float bv = bias ? bias[col] : 0.f;
#pragma unroll
        for (int i = 0; i < 4; i++) {
            int row0 = m0 + wm + i * 16 + quad * 4;
#pragma unroll
            for (int r = 0; r < 4; r++)
                C[(size_t)(row0 + r) * N + col] = acc[i][j][r] + bv;
        }
    }
}

// ---------------------------------------------------------------------------
// Main GEMM: 256x256 tile, 8-wave (2Mx4N), 8-phase pipelined, K chunks of 32
// through a 4-slot LDS FIFO per operand (4 x 16KB A + 4 x 16KB B = 128 KiB).
//
// LDS chunk layout: [256 rows][32 cols] bf16 (64 B/row), XOR-swizzled:
//   physical 16B-slot s holds data col-slot (s ^ ((row>>1)&3)).
//   gload_lds writes LINEARLY (dest = t*16); the swizzle is applied by
//   permuting the per-lane GLOBAL source column (rule #21: both-sides).
//   Read: lane(fr,quad) fetches byte row*64 + ((quad ^ ((fr>>1)&3))<<4)
//   -> each 16-lane quarter-wave spreads over all 8 bank-groups (conflict-free).
//
// Pipeline: chunk c computed in 2 phases (16 MFMA each); A(c+3) staged in the
// even phase, B(c+3) in the odd phase; vmcnt(8) gate at end of chunk c
// guarantees chunk c+1 landed (4 newest stages = 8 loads may stay in flight).
// Never vmcnt(0) in steady state.
// ---------------------------------------------------------------------------
__global__ __launch_bounds__(512, 2)
void gemm256_8p(const unsigned short* __restrict__ A,
                const unsigned short* __restrict__ B,
                float* __restrict__ C,
                const float* __restrict__ bias,
                int lda, int ldb, int N, int K, int grid_n) {
    __shared__ unsigned short lds[65536];     // 128 KiB
    const int t = threadIdx.x;

    // T1: bijective XCD swizzle (nwg % 8 == 0 by construction)
    const int nwg = gridDim.x;
    const int q8 = nwg >> 3;
    const int wg = (blockIdx.x & 7) * q8 + (blockIdx.x >> 3);
    const int m0 = (wg / grid_n) * 256;
    const int n0 = (wg % grid_n) * 256;

    const int lane = t & 63;
    const int fr = lane & 15, quad = lane >> 4;
    const int wr = t >> 8;            // wave row 0..1
    const int wc = (t >> 6) & 3;      // wave col 0..3
    const int slot16 = ((quad ^ ((fr >> 1) & 3)) << 4);   // T2 read-side swizzle

    char* ldsA = (char*)lds;           // slots: (c&3)*16384
    char* ldsB = (char*)lds + 65536;

    // staging: thread t covers rows (t>>2) and 128+(t>>2) of the 256-row tile,
    // 16 B at swizzled col; linear LDS dest = t*16 (+8192 for second sweep).
    const int srow = t >> 2;
    const int sE = ((t & 3) ^ ((t >> 3) & 3)) * 8;        // T2 source-side swizzle
    const unsigned short* aP = A + (size_t)(m0 + srow) * lda + sE;
    const unsigned short* bP = B + (size_t)(n0 + srow) * ldb + sE;
    const size_t a128 = 128 * (size_t)lda, b128 = 128 * (size_t)ldb;
    char* dA = ldsA + t * 16;
    char* dB = ldsB + t * 16;

#define STAGE_A(cc) { const unsigned short* g_ = aP + (size_t)(cc) * 32;          \
        char* d_ = dA + ((cc) & 3) * 16384;                                       \
        load_lds16(g_, d_); load_lds16(g_ + a128, d_ + 8192); }
#define STAGE_B(cc) { const unsigned short* g_ = bP + (size_t)(cc) * 32;          \
        char* d_ = dB + ((cc) & 3) * 16384;                                       \
        load_lds16(g_, d_); load_lds16(g_ + b128, d_ + 8192); }

    f32x4 acc[8][4];
#pragma unroll
    for (int i = 0; i < 8; i++)
#pragma unroll
        for (int j = 0; j < 4; j++) acc[i][j] = (f32x4){0.f, 0.f, 0.f, 0.f};

    // prologue: stage chunks 0,1,2; gate chunk 0 (8 newer loads may fly)
    STAGE_A(0); STAGE_B(0);
    STAGE_A(1); STAGE_B(1);
    STAGE_A(2); STAGE_B(2);
    asm volatile("s_waitcnt vmcnt(8)" ::: "memory");
    __builtin_amdgcn_s_barrier();

    const int NC = K >> 5;            // chunks of K=32
    const char* rA = ldsA + wr * 8192 + fr * 64 + slot16;
    const char* rB = ldsB + wc * 4096 + fr * 64 + slot16;

    for (int c = 0; c < NC; ++c) {
        const char* cA = rA + (c & 3) * 16384;
        const char* cB = rB + (c & 3) * 16384;
        bf16x8 am[4], bn[4];

        // ---------------- even phase: mf 0..3 x nf 0..3 ----------------
#pragma unroll
        for (int i = 0; i < 4; ++i) am[i] = *(const bf16x8*)(cA + i * 1024);
#pragma unroll
        for (int i = 0; i < 4; ++i) bn[i] = *(const bf16x8*)(cB + i * 1024);
        if (c + 3 < NC) STAGE_A(c + 3);
        __builtin_amdgcn_sched_barrier(0);
        __builtin_amdgcn_s_barrier();
        asm volatile("s_waitcnt lgkmcnt(0)" ::: "memory");
        __builtin_amdgcn_sched_barrier(0);
        __builtin_amdgcn_s_setprio(1);
#pragma unroll
        for (int mf = 0; mf < 4; ++mf)
#pragma unroll
            for (int nf = 0; nf < 4; ++nf)
                acc[mf][nf] = __builtin_amdgcn_mfma_f32_16x16x32_bf16(am[mf], bn[nf], acc[mf][nf], 0, 0, 0);
        __builtin_amdgcn_s_setprio(0);
        __builtin_amdgcn_sched_barrier(0);
        __builtin_amdgcn_s_barrier();

        // ---------------- odd phase: mf 4..7 x nf 0..3 ----------------
#pragma unroll
        for (int i = 0; i < 4; ++i) am[i] = *(const bf16x8*)(cA + (4 + i) * 1024);
        if (c + 3 < NC) STAGE_B(c + 3);
        __builtin_amdgcn_sched_barrier(0);
        __builtin_amdgcn_s_barrier();
        asm volatile("s_waitcnt lgkmcnt(0)" ::: "memory");
        __builtin_amdgcn_sched_barrier(0);
        __builtin_amdgcn_s_setprio(1);
#pragma unroll
        for (int mf = 0; mf < 4; ++mf)
#pragma unroll
            for (int nf = 0; nf < 4; ++nf)
                acc[4 + mf][nf] = __builtin_amdgcn_mfma_f32_16x16x32_bf16(am[mf], bn[nf], acc[4 + mf][nf], 0, 0, 0);
        __builtin_amdgcn_s_setprio(0);
        // T4 gate: ensure chunk c+1 staged; keep up to 4 stages (8 loads) in flight
        if (c < NC - 3)       { asm volatile("s_waitcnt vmcnt(8)" ::: "memory"); }
        else if (c == NC - 3) { asm volatile("s_waitcnt vmcnt(4)" ::: "memory"); }
        else if (c == NC - 2) { asm volatile("s_waitcnt vmcnt(0)" ::: "memory"); }
        __builtin_amdgcn_sched_barrier(0);
        __builtin_amdgcn_s_barrier();
    }

    // epilogue: lane(fr,quad) reg r of frag (mf,nf) ->
    //   C[m0 + wr*128 + mf*16 + quad*4 + r][n0 + wc*64 + nf*16 + fr]
#pragma unroll
    for (int nf = 0; nf < 4; ++nf) {
        int col = n0 + wc * 64 + nf * 16 + fr;
        float bv = bias ? bias[col] : 0.f;
#pragma unroll
        for (int mf = 0; mf < 8; ++mf) {
            int row0 = m0 + wr * 128 + mf * 16 + quad * 4;
#pragma unroll
            for (int r = 0; r < 4; ++r)
                C[(size_t)(row0 + r) * N + col] = acc[mf][nf][r] + bv;
        }
    }
#undef STAGE_A
#undef STAGE_B
}

// ---------------------------------------------------------------------------
extern "C" void kernel_launch(void* const* d_in, const int* in_sizes, int n_in,
                              void* d_out, int out_size, void* d_ws, size_t ws_size,
                              hipStream_t stream) {
    const float* x  = (const float*)d_in[0];   // [4,2048,4096]
    const float* W  = (const float*)d_in[1];   // [4096,4096]
    const float* b  = (const float*)d_in[2];   // [4096]
    const float* Wq = (const float*)d_in[3];   // [256,4096]
    const float* Wk = (const float*)d_in[4];   // [256,4096]
    const float* Al = (const float*)d_in[5];   // [8,16,4096]
    const float* Bm = (const float*)d_in[6];   // [8,4096,16]
    float* out = (float*)d_out;                // [4,2048,4096] fp32

    // workspace layout (bytes)
    char* ws = (char*)d_ws;
    unsigned short* Aext = (unsigned short*)ws;                          // 8192*4224*2 = 69,206,016
    unsigned short* Wext = (unsigned short*)(ws + 69206016);             // 4096*4224*2 = 34,603,008
    unsigned short* Wqka = (unsigned short*)(ws + 69206016 + 34603008);  // 640*4096*2  =  5,242,880
    float*          P    = (float*)(ws + 69206016 + 34603008 + 5242880); // 8192*640*4  = 20,971,520
    // total ~130 MB

    conv_x   <<<T_TOK * 1024 / 256, 256, 0, stream>>>((const float4*)x, Aext);
    conv_w   <<<DOUT * 1024 / 256, 256, 0, stream>>>((const float4*)W, Wext);
    fill_bm  <<<DOUT * 128 / 256, 256, 0, stream>>>(Bm, Wext);
    conv_wqka<<<NQKA * 1024 / 256, 256, 0, stream>>>((const float4*)Wq, (const float4*)Wk,
                                                     (const float4*)Al, Wqka);

    // P = x_bf16 @ Wqka^T   [8192, 640]  (128x128 kernel; N=640 not 256-divisible)
    {
        dim3 grid(NQKA / 128, T_TOK / 128);
        gemm_bt<<<grid, 256, 0, stream>>>(Aext, Wqka, P, nullptr, KEXT, 4096, NQKA, 4096);
    }

    routing<<<T_TOK, 64, 0, stream>>>(P, Aext);

    // out = A_ext @ W_ext^T + b   [8192, 4096], K = 4224 (LoRA fused in K-tail)
    // 256x256 8-phase kernel: grid = 32*16 = 512 (divisible by 8 for XCD swizzle)
    {
        int grid_n = DOUT / 256;                    // 16
        int nwg = (T_TOK / 256) * grid_n;           // 512
        gemm256_8p<<<nwg, 512, 0, stream>>>(Aext, Wext, out, b, KEXT, KEXT, DOUT, KEXT, grid_n);
    }
}